// Round 15
// baseline (449.385 us; speedup 1.0000x reference)
//
#include <hip/hip_runtime.h>

#define N_PTS 131072
#define KC    512
#define DIM   64
#define MAXIT 5
#define NCHUNK 32
#define CHUNK_PTS (N_PTS / NCHUNK)    // 4096
#define FIXSCALE 1099511627776.0      // 2^40

typedef short v8s __attribute__((ext_vector_type(8)));
typedef float v4f __attribute__((ext_vector_type(4)));

// f32 -> bf16 bits, RTNE (normals; inputs are O(1) gaussians + residuals)
__device__ __forceinline__ unsigned short bf16_rtne(float x) {
    unsigned int u = __float_as_uint(x);
    return (unsigned short)((u + 0x7FFFu + ((u >> 16) & 1u)) >> 16);
}
__device__ __forceinline__ float bf16_f32(unsigned short b) {
    return __uint_as_float(((unsigned int)b) << 16);
}
// 3-way split: x == h + m + l exactly (24 mantissa bits captured)
__device__ __forceinline__ void split3(float x, short& h, short& m, short& l) {
    unsigned short hb = bf16_rtne(x);
    float r1 = x - bf16_f32(hb);
    unsigned short mb = bf16_rtne(r1);
    float r2 = r1 - bf16_f32(mb);
    h = (short)hb; m = (short)mb; l = (short)bf16_rtne(r2);
}

// async global->LDS DMA, 16 B/lane; LDS dest = uniform base + lane*16.
__device__ __forceinline__ void gload_lds16(const unsigned short* g, void* lds) {
    __builtin_amdgcn_global_load_lds(
        (const __attribute__((address_space(1))) void*)g,
        (__attribute__((address_space(3))) void*)lds, 16, 0, 0);
}

// ---------------------------------------------------------------------------
// prep (iter 0): c2[k] (round-2 tree, bit-identical) + 3-way bf16 split of C0.
// ---------------------------------------------------------------------------
__global__ __launch_bounds__(256) void prep_kernel(
        const float* __restrict__ C, float* __restrict__ c2out,
        unsigned short* __restrict__ Ch, unsigned short* __restrict__ Cm,
        unsigned short* __restrict__ Cl) {
    int k = blockIdx.x * 256 + threadIdx.x;
    if (k < KC) {
        float sq[DIM];
        #pragma unroll
        for (int j = 0; j < DIM; ++j) {
            float c = C[k * DIM + j];
            sq[j] = c * c;
            short h, m, l;
            split3(c, h, m, l);
            Ch[k * DIM + j] = (unsigned short)h;
            Cm[k * DIM + j] = (unsigned short)m;
            Cl[k * DIM + j] = (unsigned short)l;
        }
        #pragma unroll
        for (int st = 1; st < DIM; st <<= 1)
            #pragma unroll
            for (int j = 0; j < DIM; j += 2 * st)
                sq[j] = sq[j] + sq[j + st];
        c2out[k] = sq[0];
    }
}

// ---------------------------------------------------------------------------
// assign kernel: ROUND-15 VERBATIM (419 us proven best). Final scorecard:
// occupancy {2,4,8} waves/SIMD -> {72,57,68}; barriers/chunk {31,16,2,0} ->
// {57,57,57,72}; barrier-group {4w,2w,1w} -> {57,66,72}. 256-thr/4-wave/T=2
// is the local optimum; MfmaUtil 35% reflects the serial 12-MFMA acc chain,
// unbreakable without fp-reorder (r18: ~1e-6 perturbations flip argmins).
// ---------------------------------------------------------------------------
__global__ __launch_bounds__(256, 4) void assign_kernel(
        const float* __restrict__ X,
        const unsigned short* __restrict__ Ch,
        const unsigned short* __restrict__ Cm,
        const unsigned short* __restrict__ Cl,
        const float* __restrict__ c2v, float* __restrict__ out_f) {
    __shared__ __align__(16) short Bt[2 * 6 * 64 * 8]; // 12 KB: 2 buf x 384 x v8s
    __shared__ float c2t[KC];            // 2 KB
    __shared__ float x2p[4][2][16][8];   // 4 KB
    __shared__ float x2f[4][2][16];      // 0.5 KB

    const int t   = threadIdx.x;
    const int wv  = t >> 6;
    const int l   = t & 63;
    const int row = l & 15;       // A: point-in-tile; B: center-in-tile (D col)
    const int q   = l >> 4;       // k-quad; D rows = q*4+r
    const int pbase = blockIdx.x * 128 + wv * 32;

    // B slot c in [0,384): seg = c>>6 = {Ch kc0, Ch kc1, Cm kc0, Cm kc1,
    // Cl kc0, Cl kc1}; per-lane src elem = (ct*16+row)*64 + kc*32 + q*8.
    const unsigned short* const gsrc1 =
        ((wv < 2) ? Ch : Cm) + (size_t)(row * 64 + (wv & 1) * 32 + q * 8);
    const unsigned short* const gsrc2 =
        Cl + (size_t)(row * 64 + wv * 32 + q * 8);   // used by waves 0,1 only

    v8s* const BtV = (v8s*)Bt;
    v8s* const lds1 = BtV + wv * 64;          // + buf*384 at issue
    v8s* const lds2 = BtV + 256 + wv * 64;

    // issue tile-0 DMA immediately: completes under A-fragment build
    gload_lds16(gsrc1, lds1);
    if (wv < 2) gload_lds16(gsrc2, lds2);

    // stage c2 into LDS once
    for (int i = t; i < KC; i += 256) c2t[i] = c2v[i];

    // ---- A fragments (3 splits x 2 k-chunks x 2 point-tiles) + x2 partials
    v8s ah[2][2], am[2][2], al[2][2];
    #pragma unroll
    for (int T = 0; T < 2; ++T) {
        const float* xr = X + (size_t)(pbase + T * 16 + row) * DIM + q * 8;
        #pragma unroll
        for (int kc = 0; kc < 2; ++kc) {
            float4 v0 = *(const float4*)(xr + kc * 32);
            float4 v1 = *(const float4*)(xr + kc * 32 + 4);
            float e[8] = { v0.x, v0.y, v0.z, v0.w, v1.x, v1.y, v1.z, v1.w };
            v8s H, M, L;
            #pragma unroll
            for (int j = 0; j < 8; ++j) {
                short hh, mm, ll;
                split3(e[j], hh, mm, ll);
                H[j] = hh; M[j] = mm; L[j] = ll;
            }
            ah[T][kc] = H; am[T][kc] = M; al[T][kc] = L;
            // aligned 8-leaf subtree of the round-2 x2 tree (exact order)
            float s0 = e[0]*e[0], s1 = e[1]*e[1], s2 = e[2]*e[2], s3 = e[3]*e[3];
            float s4 = e[4]*e[4], s5 = e[5]*e[5], s6 = e[6]*e[6], s7 = e[7]*e[7];
            x2p[wv][T][row][kc * 4 + q] =
                ((s0 + s1) + (s2 + s3)) + ((s4 + s5) + (s6 + s7));
        }
    }
    __syncthreads();                       // x2p ready; tile-0 DMA drained
    if (t < 128) {   // 4 waves x 2 T x 16 rows (same tree as r2-r25)
        int w2 = t >> 5, T2 = (t >> 4) & 1, pt = t & 15;
        const float* P = x2p[w2][T2][pt];
        x2f[w2][T2][pt] = ((P[0] + P[1]) + (P[2] + P[3]))
                        + ((P[4] + P[5]) + (P[6] + P[7]));
    }
    __syncthreads();                       // x2f + buf0 ready
    float x2x[2][4];
    #pragma unroll
    for (int T = 0; T < 2; ++T)
        #pragma unroll
        for (int r = 0; r < 4; ++r)
            x2x[T][r] = x2f[wv][T][q * 4 + r];

    float bd[2][4];
    int   bk[2][4];
    #pragma unroll
    for (int T = 0; T < 2; ++T)
        #pragma unroll
        for (int r = 0; r < 4; ++r) { bd[T][r] = 3.4e38f; bk[T][r] = 0; }

    for (int ct = 0; ct < 32; ++ct) {
        const int cur = ct & 1;
        if (ct < 31) {                     // DMA tile ct+1 -> other buffer;
            const size_t goff = (size_t)(ct + 1) * 1024;   // in flight over GEMM
            gload_lds16(gsrc1 + goff, lds1 + (cur ^ 1) * 384);
            if (wv < 2) gload_lds16(gsrc2 + goff, lds2 + (cur ^ 1) * 384);
        }
        v8s* const rb = BtV + cur * 384;
        v8s bh0 = rb[0 * 64 + l];
        v8s bh1 = rb[1 * 64 + l];
        v8s bm0 = rb[2 * 64 + l];
        v8s bm1 = rb[3 * 64 + l];
        v8s bl0 = rb[4 * 64 + l];
        v8s bl1 = rb[5 * 64 + l];
        float c2k = c2t[ct * 16 + row];

        #pragma unroll
        for (int T = 0; T < 2; ++T) {
            v4f acc = {0.f, 0.f, 0.f, 0.f};
            acc = __builtin_amdgcn_mfma_f32_16x16x32_bf16(ah[T][0], bh0, acc, 0, 0, 0);
            acc = __builtin_amdgcn_mfma_f32_16x16x32_bf16(ah[T][1], bh1, acc, 0, 0, 0);
            acc = __builtin_amdgcn_mfma_f32_16x16x32_bf16(am[T][0], bh0, acc, 0, 0, 0);
            acc = __builtin_amdgcn_mfma_f32_16x16x32_bf16(am[T][1], bh1, acc, 0, 0, 0);
            acc = __builtin_amdgcn_mfma_f32_16x16x32_bf16(ah[T][0], bm0, acc, 0, 0, 0);
            acc = __builtin_amdgcn_mfma_f32_16x16x32_bf16(ah[T][1], bm1, acc, 0, 0, 0);
            acc = __builtin_amdgcn_mfma_f32_16x16x32_bf16(am[T][0], bm0, acc, 0, 0, 0);
            acc = __builtin_amdgcn_mfma_f32_16x16x32_bf16(am[T][1], bm1, acc, 0, 0, 0);
            acc = __builtin_amdgcn_mfma_f32_16x16x32_bf16(al[T][0], bh0, acc, 0, 0, 0);
            acc = __builtin_amdgcn_mfma_f32_16x16x32_bf16(al[T][1], bh1, acc, 0, 0, 0);
            acc = __builtin_amdgcn_mfma_f32_16x16x32_bf16(ah[T][0], bl0, acc, 0, 0, 0);
            acc = __builtin_amdgcn_mfma_f32_16x16x32_bf16(ah[T][1], bl1, acc, 0, 0, 0);
            #pragma unroll
            for (int r = 0; r < 4; ++r) {
                float tt = x2x[T][r] + c2k;
                float d2 = fmaf(-2.0f, acc[r], tt);
                if (d2 < bd[T][r]) { bd[T][r] = d2; bk[T][r] = ct * 16 + row; }
            }
        }
        if (ct < 31) __syncthreads();      // drains a long-complete DMA; swaps buf
    }

    // ---- cross-lane argmin over the 16 center residues (lane bits 0..3)
    #pragma unroll
    for (int T = 0; T < 2; ++T)
        #pragma unroll
        for (int r = 0; r < 4; ++r) {
            unsigned int b = __float_as_uint(bd[T][r]);
            b = (b & 0x80000000u) ? ~b : (b | 0x80000000u);
            unsigned long long key = ((unsigned long long)b << 32)
                                   | (unsigned int)bk[T][r];
            #pragma unroll
            for (int st = 1; st <= 8; st <<= 1) {
                unsigned long long o = __shfl_xor(key, st, 64);
                if (o < key) key = o;
            }
            if (row == 0) {
                int p = pbase + T * 16 + q * 4 + r;
                out_f[p] = (float)((int)(unsigned int)key);
            }
        }
}

// ---------------------------------------------------------------------------
// accumulate, ROUND 26: 8-way dim split at NCHUNK=32 -> grid 256 (FULL CU
// coverage; r24's 128 blocks idled half the machine and doubled the
// point-loop to ~11 us). Each block: 8 dims (2 lanes/point, float4 loads
// kept), 8 passes x 512 points. Flush total unchanged (256 blk x 4096 slot
// = 1.05M atomics ~ 8.4 MB, the r24-proven optimum). LDS 36.9 KB pad-9:
// lsum[a*9+dl] -> bank (18a+2dl) mod 32, spread by random a. Integer adds
// order-independent -> bit-identical.
// ---------------------------------------------------------------------------
__global__ __launch_bounds__(1024) void accum_kernel(
        const float* __restrict__ X, const float* __restrict__ af,
        unsigned long long* __restrict__ qsums, int* __restrict__ counts) {
    __shared__ unsigned long long lsum[KC * 9];    // pad-9: 36.9 KB
    __shared__ int lcnt[KC];
    int slice = blockIdx.x & 7;       // 8 dims: slice*8 .. slice*8+7
    int chunk = blockIdx.x >> 3;
    int p4 = threadIdx.x >> 1;        // 0..511: point-in-pass
    int c2 = threadIdx.x & 1;         // float4 half within the 8-dim slice

    for (int i = threadIdx.x; i < KC * 9; i += 1024) lsum[i] = 0ull;
    for (int i = threadIdx.x; i < KC; i += 1024) lcnt[i] = 0;
    __syncthreads();

    int base = chunk * CHUNK_PTS;
    #pragma unroll 2
    for (int it = 0; it < CHUNK_PTS / 512; ++it) {    // 8 passes
        int n = base + it * 512 + p4;
        int a = (int)af[n];
        float4 xv = *(const float4*)(X + (size_t)n * DIM + slice * 8 + c2 * 4);
        long long q0 = (long long)llrint((double)xv.x * FIXSCALE);
        long long q1 = (long long)llrint((double)xv.y * FIXSCALE);
        long long q2 = (long long)llrint((double)xv.z * FIXSCALE);
        long long q3 = (long long)llrint((double)xv.w * FIXSCALE);
        atomicAdd(&lsum[a * 9 + c2 * 4 + 0], (unsigned long long)q0);
        atomicAdd(&lsum[a * 9 + c2 * 4 + 1], (unsigned long long)q1);
        atomicAdd(&lsum[a * 9 + c2 * 4 + 2], (unsigned long long)q2);
        atomicAdd(&lsum[a * 9 + c2 * 4 + 3], (unsigned long long)q3);
        if (slice == 0 && c2 == 0) atomicAdd(&lcnt[a], 1);
    }
    __syncthreads();

    // flush: slice-major qsums [8][KC][8]; i linear in tid -> contiguous u64
    unsigned long long* qs = qsums + (size_t)slice * (KC * 8);
    for (int i = threadIdx.x; i < KC * 8; i += 1024) {
        unsigned long long v = lsum[(i >> 3) * 9 + (i & 7)];
        if (v != 0ull) atomicAdd(&qs[i], v);
    }
    if (slice == 0)
        for (int i = threadIdx.x; i < KC; i += 1024) {
            int v = lcnt[i];
            if (v != 0) atomicAdd(&counts[i], v);
        }
}

// ---------------------------------------------------------------------------
// update: centers = sums/max(cnt,1), ==0 -> re-seed; writes f32 centers to
// d_out tail, next iter's c2 (same butterfly tree) + 3-way bf16 splits.
// Reads slice-major qsums [8][KC][8]; self-zeroes qsums/counts for the
// next iteration (replaces per-iter memsets; same-lane read-then-write).
// ---------------------------------------------------------------------------
__global__ __launch_bounds__(256) void update_kernel(
        unsigned long long* __restrict__ qsums,
        int* __restrict__ counts,
        const int* __restrict__ repl, const float* __restrict__ X,
        float* __restrict__ outC, float* __restrict__ c2v,
        unsigned short* __restrict__ Ch, unsigned short* __restrict__ Cm,
        unsigned short* __restrict__ Cl) {
    int k = blockIdx.x * 4 + (threadIdx.x >> 6);
    int d = threadIdx.x & 63;

    size_t qi = (size_t)(d >> 3) * (KC * 8) + k * 8 + (d & 7);
    long long qq = (long long)qsums[qi];
    qsums[qi] = 0ull;                             // ready for next iter
    float s = (float)((double)qq * (1.0 / FIXSCALE));
    float cnt = (float)counts[k];
    float v = s / fmaxf(cnt, 1.0f);
    if (v == 0.0f) v = X[(size_t)repl[k] * DIM + d];
    outC[k * DIM + d] = v;

    short h, m, l;
    split3(v, h, m, l);
    Ch[k * DIM + d] = (unsigned short)h;
    Cm[k * DIM + d] = (unsigned short)m;
    Cl[k * DIM + d] = (unsigned short)l;

    float sq = v * v;
    #pragma unroll
    for (int st = 1; st < 64; st <<= 1)
        sq += __shfl_xor(sq, st, 64);
    if (d == 0) {
        c2v[k] = sq;
        counts[k] = 0;                            // ready for next iter
    }
}

// ---------------------------------------------------------------------------
extern "C" void kernel_launch(void* const* d_in, const int* in_sizes, int n_in,
                              void* d_out, int out_size, void* d_ws, size_t ws_size,
                              hipStream_t stream) {
    const float* X    = (const float*)d_in[0];   // [N, D]
    const float* C0   = (const float*)d_in[1];   // [K, D]
    const int*   repl = (const int*)d_in[2];     // [MAXIT, K]
    float* out = (float*)d_out;                  // [N] assignments + [K*D] centers

    // ws: 452 KB total
    char* ws = (char*)d_ws;
    unsigned short* Ch = (unsigned short*)(ws + 0);            // 64 KB
    unsigned short* Cm = (unsigned short*)(ws + (64 << 10));   // 64 KB
    unsigned short* Cl = (unsigned short*)(ws + (128 << 10));  // 64 KB
    unsigned long long* qsums = (unsigned long long*)(ws + (192 << 10)); // 256 KB
    int*   counts = (int*)  (ws + (448 << 10));                // 2 KB
    float* c2v    = (float*)(ws + (450 << 10));                // 2 KB

    prep_kernel<<<2, 256, 0, stream>>>(C0, c2v, Ch, Cm, Cl);

    // one-time zero; update_kernel re-zeroes for subsequent iterations
    hipMemsetAsync(qsums, 0, KC * DIM * sizeof(unsigned long long)
                             + KC * sizeof(int), stream);

    for (int i = 0; i < MAXIT; ++i) {
        assign_kernel<<<N_PTS / 128, 256, 0, stream>>>(
            X, Ch, Cm, Cl, c2v, out);

        accum_kernel<<<NCHUNK * 8, 1024, 0, stream>>>(X, out, qsums, counts);

        update_kernel<<<KC / 4, 256, 0, stream>>>(
            qsums, counts, repl + i * KC, X, out + N_PTS, c2v, Ch, Cm, Cl);
    }
}

// Round 17
// 418.313 us; speedup vs baseline: 1.0743x; 1.0743x over previous
//
#include <hip/hip_runtime.h>

#define N_PTS 131072
#define KC    512
#define DIM   64
#define MAXIT 5
#define NCHUNK 32
#define CHUNK_PTS (N_PTS / NCHUNK)    // 4096
#define FIXSCALE 1099511627776.0      // 2^40

typedef short v8s __attribute__((ext_vector_type(8)));
typedef float v4f __attribute__((ext_vector_type(4)));

// f32 -> bf16 bits, RTNE (normals; inputs are O(1) gaussians + residuals)
__device__ __forceinline__ unsigned short bf16_rtne(float x) {
    unsigned int u = __float_as_uint(x);
    return (unsigned short)((u + 0x7FFFu + ((u >> 16) & 1u)) >> 16);
}
__device__ __forceinline__ float bf16_f32(unsigned short b) {
    return __uint_as_float(((unsigned int)b) << 16);
}
// 3-way split: x == h + m + l exactly (24 mantissa bits captured)
__device__ __forceinline__ void split3(float x, short& h, short& m, short& l) {
    unsigned short hb = bf16_rtne(x);
    float r1 = x - bf16_f32(hb);
    unsigned short mb = bf16_rtne(r1);
    float r2 = r1 - bf16_f32(mb);
    h = (short)hb; m = (short)mb; l = (short)bf16_rtne(r2);
}

// async global->LDS DMA, 16 B/lane; LDS dest = uniform base + lane*16.
__device__ __forceinline__ void gload_lds16(const unsigned short* g, void* lds) {
    __builtin_amdgcn_global_load_lds(
        (const __attribute__((address_space(1))) void*)g,
        (__attribute__((address_space(3))) void*)lds, 16, 0, 0);
}

// ---------------------------------------------------------------------------
// prep (iter 0): c2[k] (round-2 tree, bit-identical) + 3-way bf16 split of C0.
// ---------------------------------------------------------------------------
__global__ __launch_bounds__(256) void prep_kernel(
        const float* __restrict__ C, float* __restrict__ c2out,
        unsigned short* __restrict__ Ch, unsigned short* __restrict__ Cm,
        unsigned short* __restrict__ Cl) {
    int k = blockIdx.x * 256 + threadIdx.x;
    if (k < KC) {
        float sq[DIM];
        #pragma unroll
        for (int j = 0; j < DIM; ++j) {
            float c = C[k * DIM + j];
            sq[j] = c * c;
            short h, m, l;
            split3(c, h, m, l);
            Ch[k * DIM + j] = (unsigned short)h;
            Cm[k * DIM + j] = (unsigned short)m;
            Cl[k * DIM + j] = (unsigned short)l;
        }
        #pragma unroll
        for (int st = 1; st < DIM; st <<= 1)
            #pragma unroll
            for (int j = 0; j < DIM; j += 2 * st)
                sq[j] = sq[j] + sq[j + st];
        c2out[k] = sq[0];
    }
}

// ---------------------------------------------------------------------------
// assign kernel: ROUND-15 VERBATIM (419 us proven best). Final scorecard:
// occupancy {2,4,8} waves/SIMD -> {72,57,68}; barriers/chunk {31,16,2,0} ->
// {57,57,57,72}; barrier-group {4w,2w,1w} -> {57,66,72}. 256-thr/4-wave/T=2
// is the local optimum; MfmaUtil 35% reflects the serial 12-MFMA acc chain,
// unbreakable without fp-reorder (r18: ~1e-6 perturbations flip argmins).
// ---------------------------------------------------------------------------
__global__ __launch_bounds__(256, 4) void assign_kernel(
        const float* __restrict__ X,
        const unsigned short* __restrict__ Ch,
        const unsigned short* __restrict__ Cm,
        const unsigned short* __restrict__ Cl,
        const float* __restrict__ c2v, float* __restrict__ out_f) {
    __shared__ __align__(16) short Bt[2 * 6 * 64 * 8]; // 12 KB: 2 buf x 384 x v8s
    __shared__ float c2t[KC];            // 2 KB
    __shared__ float x2p[4][2][16][8];   // 4 KB
    __shared__ float x2f[4][2][16];      // 0.5 KB

    const int t   = threadIdx.x;
    const int wv  = t >> 6;
    const int l   = t & 63;
    const int row = l & 15;       // A: point-in-tile; B: center-in-tile (D col)
    const int q   = l >> 4;       // k-quad; D rows = q*4+r
    const int pbase = blockIdx.x * 128 + wv * 32;

    // B slot c in [0,384): seg = c>>6 = {Ch kc0, Ch kc1, Cm kc0, Cm kc1,
    // Cl kc0, Cl kc1}; per-lane src elem = (ct*16+row)*64 + kc*32 + q*8.
    const unsigned short* const gsrc1 =
        ((wv < 2) ? Ch : Cm) + (size_t)(row * 64 + (wv & 1) * 32 + q * 8);
    const unsigned short* const gsrc2 =
        Cl + (size_t)(row * 64 + wv * 32 + q * 8);   // used by waves 0,1 only

    v8s* const BtV = (v8s*)Bt;
    v8s* const lds1 = BtV + wv * 64;          // + buf*384 at issue
    v8s* const lds2 = BtV + 256 + wv * 64;

    // issue tile-0 DMA immediately: completes under A-fragment build
    gload_lds16(gsrc1, lds1);
    if (wv < 2) gload_lds16(gsrc2, lds2);

    // stage c2 into LDS once
    for (int i = t; i < KC; i += 256) c2t[i] = c2v[i];

    // ---- A fragments (3 splits x 2 k-chunks x 2 point-tiles) + x2 partials
    v8s ah[2][2], am[2][2], al[2][2];
    #pragma unroll
    for (int T = 0; T < 2; ++T) {
        const float* xr = X + (size_t)(pbase + T * 16 + row) * DIM + q * 8;
        #pragma unroll
        for (int kc = 0; kc < 2; ++kc) {
            float4 v0 = *(const float4*)(xr + kc * 32);
            float4 v1 = *(const float4*)(xr + kc * 32 + 4);
            float e[8] = { v0.x, v0.y, v0.z, v0.w, v1.x, v1.y, v1.z, v1.w };
            v8s H, M, L;
            #pragma unroll
            for (int j = 0; j < 8; ++j) {
                short hh, mm, ll;
                split3(e[j], hh, mm, ll);
                H[j] = hh; M[j] = mm; L[j] = ll;
            }
            ah[T][kc] = H; am[T][kc] = M; al[T][kc] = L;
            // aligned 8-leaf subtree of the round-2 x2 tree (exact order)
            float s0 = e[0]*e[0], s1 = e[1]*e[1], s2 = e[2]*e[2], s3 = e[3]*e[3];
            float s4 = e[4]*e[4], s5 = e[5]*e[5], s6 = e[6]*e[6], s7 = e[7]*e[7];
            x2p[wv][T][row][kc * 4 + q] =
                ((s0 + s1) + (s2 + s3)) + ((s4 + s5) + (s6 + s7));
        }
    }
    __syncthreads();                       // x2p ready; tile-0 DMA drained
    if (t < 128) {   // 4 waves x 2 T x 16 rows (same tree as r2-r26)
        int w2 = t >> 5, T2 = (t >> 4) & 1, pt = t & 15;
        const float* P = x2p[w2][T2][pt];
        x2f[w2][T2][pt] = ((P[0] + P[1]) + (P[2] + P[3]))
                        + ((P[4] + P[5]) + (P[6] + P[7]));
    }
    __syncthreads();                       // x2f + buf0 ready
    float x2x[2][4];
    #pragma unroll
    for (int T = 0; T < 2; ++T)
        #pragma unroll
        for (int r = 0; r < 4; ++r)
            x2x[T][r] = x2f[wv][T][q * 4 + r];

    float bd[2][4];
    int   bk[2][4];
    #pragma unroll
    for (int T = 0; T < 2; ++T)
        #pragma unroll
        for (int r = 0; r < 4; ++r) { bd[T][r] = 3.4e38f; bk[T][r] = 0; }

    for (int ct = 0; ct < 32; ++ct) {
        const int cur = ct & 1;
        if (ct < 31) {                     // DMA tile ct+1 -> other buffer;
            const size_t goff = (size_t)(ct + 1) * 1024;   // in flight over GEMM
            gload_lds16(gsrc1 + goff, lds1 + (cur ^ 1) * 384);
            if (wv < 2) gload_lds16(gsrc2 + goff, lds2 + (cur ^ 1) * 384);
        }
        v8s* const rb = BtV + cur * 384;
        v8s bh0 = rb[0 * 64 + l];
        v8s bh1 = rb[1 * 64 + l];
        v8s bm0 = rb[2 * 64 + l];
        v8s bm1 = rb[3 * 64 + l];
        v8s bl0 = rb[4 * 64 + l];
        v8s bl1 = rb[5 * 64 + l];
        float c2k = c2t[ct * 16 + row];

        #pragma unroll
        for (int T = 0; T < 2; ++T) {
            v4f acc = {0.f, 0.f, 0.f, 0.f};
            acc = __builtin_amdgcn_mfma_f32_16x16x32_bf16(ah[T][0], bh0, acc, 0, 0, 0);
            acc = __builtin_amdgcn_mfma_f32_16x16x32_bf16(ah[T][1], bh1, acc, 0, 0, 0);
            acc = __builtin_amdgcn_mfma_f32_16x16x32_bf16(am[T][0], bh0, acc, 0, 0, 0);
            acc = __builtin_amdgcn_mfma_f32_16x16x32_bf16(am[T][1], bh1, acc, 0, 0, 0);
            acc = __builtin_amdgcn_mfma_f32_16x16x32_bf16(ah[T][0], bm0, acc, 0, 0, 0);
            acc = __builtin_amdgcn_mfma_f32_16x16x32_bf16(ah[T][1], bm1, acc, 0, 0, 0);
            acc = __builtin_amdgcn_mfma_f32_16x16x32_bf16(am[T][0], bm0, acc, 0, 0, 0);
            acc = __builtin_amdgcn_mfma_f32_16x16x32_bf16(am[T][1], bm1, acc, 0, 0, 0);
            acc = __builtin_amdgcn_mfma_f32_16x16x32_bf16(al[T][0], bh0, acc, 0, 0, 0);
            acc = __builtin_amdgcn_mfma_f32_16x16x32_bf16(al[T][1], bh1, acc, 0, 0, 0);
            acc = __builtin_amdgcn_mfma_f32_16x16x32_bf16(ah[T][0], bl0, acc, 0, 0, 0);
            acc = __builtin_amdgcn_mfma_f32_16x16x32_bf16(ah[T][1], bl1, acc, 0, 0, 0);
            #pragma unroll
            for (int r = 0; r < 4; ++r) {
                float tt = x2x[T][r] + c2k;
                float d2 = fmaf(-2.0f, acc[r], tt);
                if (d2 < bd[T][r]) { bd[T][r] = d2; bk[T][r] = ct * 16 + row; }
            }
        }
        if (ct < 31) __syncthreads();      // drains a long-complete DMA; swaps buf
    }

    // ---- cross-lane argmin over the 16 center residues (lane bits 0..3)
    #pragma unroll
    for (int T = 0; T < 2; ++T)
        #pragma unroll
        for (int r = 0; r < 4; ++r) {
            unsigned int b = __float_as_uint(bd[T][r]);
            b = (b & 0x80000000u) ? ~b : (b | 0x80000000u);
            unsigned long long key = ((unsigned long long)b << 32)
                                   | (unsigned int)bk[T][r];
            #pragma unroll
            for (int st = 1; st <= 8; st <<= 1) {
                unsigned long long o = __shfl_xor(key, st, 64);
                if (o < key) key = o;
            }
            if (row == 0) {
                int p = pbase + T * 16 + q * 4 + r;
                out_f[p] = (float)((int)(unsigned int)key);
            }
        }
}

// ---------------------------------------------------------------------------
// accumulate: ROUND-24 VERBATIM (NCHUNK=32, 128 blocks x 1024 thr; pad-17
// LDS, slice-major contiguous u64 flush). Proven 419.4 us. Design space
// closed: NCHUNK {64,32} -> {456,419}; dim-split {4,8} -> {419,449} (8-way
// halves the per-block cache-line coverage -> 2x X fetch). s=4 is the
// 64-B-line-aligned optimum; t(c)=349/c+0.284c minimized at c~32.
// ---------------------------------------------------------------------------
__global__ __launch_bounds__(1024) void accum_kernel(
        const float* __restrict__ X, const float* __restrict__ af,
        unsigned long long* __restrict__ qsums, int* __restrict__ counts) {
    __shared__ unsigned long long lsum[KC * 17];   // pad-17: 69.6 KB
    __shared__ int lcnt[KC];
    int slice = blockIdx.x & 3;
    int chunk = blockIdx.x >> 2;
    int p4 = threadIdx.x >> 2;        // 0..255: point-in-pass
    int c4 = threadIdx.x & 3;         // dim quad within 16-dim slice

    for (int i = threadIdx.x; i < KC * 17; i += 1024) lsum[i] = 0ull;
    for (int i = threadIdx.x; i < KC; i += 1024) lcnt[i] = 0;
    __syncthreads();

    int base = chunk * CHUNK_PTS;
    #pragma unroll 2
    for (int it = 0; it < CHUNK_PTS / 256; ++it) {    // 16 passes
        int n = base + it * 256 + p4;
        int a = (int)af[n];
        float4 xv = *(const float4*)(X + (size_t)n * DIM + slice * 16 + c4 * 4);
        long long q0 = (long long)llrint((double)xv.x * FIXSCALE);
        long long q1 = (long long)llrint((double)xv.y * FIXSCALE);
        long long q2 = (long long)llrint((double)xv.z * FIXSCALE);
        long long q3 = (long long)llrint((double)xv.w * FIXSCALE);
        atomicAdd(&lsum[a * 17 + c4 * 4 + 0], (unsigned long long)q0);
        atomicAdd(&lsum[a * 17 + c4 * 4 + 1], (unsigned long long)q1);
        atomicAdd(&lsum[a * 17 + c4 * 4 + 2], (unsigned long long)q2);
        atomicAdd(&lsum[a * 17 + c4 * 4 + 3], (unsigned long long)q3);
        if (slice == 0 && c4 == 0) atomicAdd(&lcnt[a], 1);
    }
    __syncthreads();

    // flush: slice-major qsums; i linear in tid -> contiguous u64 atomics
    unsigned long long* qs = qsums + (size_t)slice * (KC * 16);
    for (int i = threadIdx.x; i < KC * 16; i += 1024) {
        unsigned long long v = lsum[(i >> 4) * 17 + (i & 15)];
        if (v != 0ull) atomicAdd(&qs[i], v);
    }
    if (slice == 0)
        for (int i = threadIdx.x; i < KC; i += 1024) {
            int v = lcnt[i];
            if (v != 0) atomicAdd(&counts[i], v);
        }
}

// ---------------------------------------------------------------------------
// update: centers = sums/max(cnt,1), ==0 -> re-seed; writes f32 centers to
// d_out tail, next iter's c2 (same butterfly tree) + 3-way bf16 splits.
// Reads slice-major qsums [4][KC][16]; self-zeroes qsums/counts for the
// next iteration (replaces per-iter memsets; same-lane read-then-write).
// ---------------------------------------------------------------------------
__global__ __launch_bounds__(256) void update_kernel(
        unsigned long long* __restrict__ qsums,
        int* __restrict__ counts,
        const int* __restrict__ repl, const float* __restrict__ X,
        float* __restrict__ outC, float* __restrict__ c2v,
        unsigned short* __restrict__ Ch, unsigned short* __restrict__ Cm,
        unsigned short* __restrict__ Cl) {
    int k = blockIdx.x * 4 + (threadIdx.x >> 6);
    int d = threadIdx.x & 63;

    size_t qi = (size_t)(d >> 4) * (KC * 16) + k * 16 + (d & 15);
    long long qq = (long long)qsums[qi];
    qsums[qi] = 0ull;                             // ready for next iter
    float s = (float)((double)qq * (1.0 / FIXSCALE));
    float cnt = (float)counts[k];
    float v = s / fmaxf(cnt, 1.0f);
    if (v == 0.0f) v = X[(size_t)repl[k] * DIM + d];
    outC[k * DIM + d] = v;

    short h, m, l;
    split3(v, h, m, l);
    Ch[k * DIM + d] = (unsigned short)h;
    Cm[k * DIM + d] = (unsigned short)m;
    Cl[k * DIM + d] = (unsigned short)l;

    float sq = v * v;
    #pragma unroll
    for (int st = 1; st < 64; st <<= 1)
        sq += __shfl_xor(sq, st, 64);
    if (d == 0) {
        c2v[k] = sq;
        counts[k] = 0;                            // ready for next iter
    }
}

// ---------------------------------------------------------------------------
extern "C" void kernel_launch(void* const* d_in, const int* in_sizes, int n_in,
                              void* d_out, int out_size, void* d_ws, size_t ws_size,
                              hipStream_t stream) {
    const float* X    = (const float*)d_in[0];   // [N, D]
    const float* C0   = (const float*)d_in[1];   // [K, D]
    const int*   repl = (const int*)d_in[2];     // [MAXIT, K]
    float* out = (float*)d_out;                  // [N] assignments + [K*D] centers

    // ws: 452 KB total
    char* ws = (char*)d_ws;
    unsigned short* Ch = (unsigned short*)(ws + 0);            // 64 KB
    unsigned short* Cm = (unsigned short*)(ws + (64 << 10));   // 64 KB
    unsigned short* Cl = (unsigned short*)(ws + (128 << 10));  // 64 KB
    unsigned long long* qsums = (unsigned long long*)(ws + (192 << 10)); // 256 KB
    int*   counts = (int*)  (ws + (448 << 10));                // 2 KB
    float* c2v    = (float*)(ws + (450 << 10));                // 2 KB

    prep_kernel<<<2, 256, 0, stream>>>(C0, c2v, Ch, Cm, Cl);

    // one-time zero; update_kernel re-zeroes for subsequent iterations
    hipMemsetAsync(qsums, 0, KC * DIM * sizeof(unsigned long long)
                             + KC * sizeof(int), stream);

    for (int i = 0; i < MAXIT; ++i) {
        assign_kernel<<<N_PTS / 128, 256, 0, stream>>>(
            X, Ch, Cm, Cl, c2v, out);

        accum_kernel<<<NCHUNK * 4, 1024, 0, stream>>>(X, out, qsums, counts);

        update_kernel<<<KC / 4, 256, 0, stream>>>(
            qsums, counts, repl + i * KC, X, out + N_PTS, c2v, Ch, Cm, Cl);
    }
}